// Round 17
// baseline (11837.095 us; speedup 1.0000x reference)
//
#include <hip/hip_runtime.h>

typedef _Float16 f16x8 __attribute__((ext_vector_type(8)));
typedef _Float16 f16x4 __attribute__((ext_vector_type(4)));
typedef float    f32x4 __attribute__((ext_vector_type(4)));

#define DEVINL __device__ __forceinline__

namespace {
constexpr int Tt = 256, Ff = 128, Hh = 256, Uu = 512, OUTo = 128;
constexpr int NCLUST = 32;               // 512 / 16 row-groups
constexpr int CBLK = 8;                  // blocks per cluster
constexpr int NSLOT = 68;                // frags per (cb,wq): 12 W1 + 16 W2 + 32 heads + 8 Wout
constexpr int NFRAG = CBLK * 4 * NSLOT;  // 2176
constexpr size_t WFRAG_BYTES = (size_t)NFRAG * 1024;
constexpr size_t ACT_OFF = WFRAG_BYTES;
constexpr size_t ACT_STRIDE = 40960;     // z1 16K | z2 16K | h 8K (+pad)
constexpr size_t CNT_OFF = ACT_OFF + (size_t)NCLUST * ACT_STRIDE;
constexpr size_t CNT_BYTES = (size_t)NCLUST * 8 * 4;
// dynamic LDS per quad: stgz 16640 | stgh 8448 | taL 8704
constexpr int STGZ_Q = 16640, STGH_Q = 8448, TAL_Q = 8704;
constexpr int DYN_BYTES = 4 * (STGZ_Q + STGH_Q + TAL_Q);   // 135168
}

// ---- weight prep: f32 row-major -> per-(cb,wq) fp16 MFMA fragment banks ----
__global__ void prep_weights(const float* __restrict__ W1, const float* __restrict__ W2,
                             const float* __restrict__ Wff1, const float* __restrict__ Wff2,
                             const float* __restrict__ Wta, const float* __restrict__ Wtb,
                             const float* __restrict__ Wout, _Float16* __restrict__ ws)
{
    int o = blockIdx.x * blockDim.x + threadIdx.x;
    if (o >= NFRAG * 512) return;
    int j = o & 7, l = (o >> 3) & 63, r = o >> 9;
    int slot = r % NSLOT, bw = r / NSLOT;
    int w = bw & 3, cb = bw >> 2;
    int k_in = ((l >> 4) << 3) + j, lc = l & 15;
    float v;
    if (slot < 12) {
        int kt = slot;
        v = W1[(kt * 32 + k_in) * Uu + cb * 64 + w * 16 + lc];
    } else if (slot < 28) {
        int kt = slot - 12;
        v = W2[(kt * 32 + k_in) * Uu + cb * 64 + w * 16 + lc];
    } else if (slot < 60) {
        int s = slot - 28, hpL = s >> 4, kt = s & 15;
        int head = (w & 1) * 2 + hpL;
        const float* W = (head == 0) ? Wff1 : (head == 1) ? Wff2 : (head == 2) ? Wta : Wtb;
        v = W[(kt * 32 + k_in) * Hh + cb * 32 + (w >> 1) * 16 + lc];
    } else {
        int kt = slot - 60;
        v = Wout[(kt * 32 + k_in) * OUTo + cb * 16 + lc];
    }
    ws[o] = (_Float16)v;
}

DEVINL float fast_tanh(float v) {
    float e = __expf(2.0f * v);
    return 1.0f - 2.0f / (e + 1.0f);
}
DEVINL float fast_sigmoid(float v) { return 1.0f / (1.0f + __expf(-v)); }
DEVINL float lecun_act(float v)    { return 1.7159f * fast_tanh(0.666f * v); }

DEVINL void stg8_dev(_Float16* p, f16x4 v) {
    asm volatile("global_store_dwordx2 %0, %1, off sc1" :: "v"(p), "v"(v) : "memory");
}

#define GATHER4(g0, g1, g2, g3, base) \
    asm volatile( \
        "global_load_dwordx4 %0, %4, off sc1\n\t" \
        "global_load_dwordx4 %1, %5, off sc1\n\t" \
        "global_load_dwordx4 %2, %6, off sc1\n\t" \
        "global_load_dwordx4 %3, %7, off sc1\n\t" \
        "s_waitcnt vmcnt(0)" \
        : "=&v"(g0), "=&v"(g1), "=&v"(g2), "=&v"(g3) \
        : "v"(base), "v"((base) + 4096), "v"((base) + 8192), "v"((base) + 12288) \
        : "memory")

#define GATHER2(g0, g1, base) \
    asm volatile( \
        "global_load_dwordx4 %0, %2, off sc1\n\t" \
        "global_load_dwordx4 %1, %3, off sc1\n\t" \
        "s_waitcnt vmcnt(0)" \
        : "=&v"(g0), "=&v"(g1) \
        : "v"(base), "v"((base) + 4096) \
        : "memory")

#define MFMA16(a, b, c) __builtin_amdgcn_mfma_f32_16x16x32_f16(a, b, c, 0, 0, 0)

// ---- quad-scoped barriers ----
// hq slots: [0..3] phase-arr | [4] go | [5],[6] p3 pair | [8..11] local-bar arr

// local (LDS-only) quad barrier: all 4 waves' LDS writes visible
DEVINL void lb_bar(volatile int* hq, int wq, int l, int tag) {
    asm volatile("s_waitcnt lgkmcnt(0)" ::: "memory");
    if (l == 0) hq[8 + wq] = tag;
    for (;;) {
        int a0 = hq[8], a1 = hq[9], a2 = hq[10], a3 = hq[11];
        if (min(min(a0, a1), min(a2, a3)) >= tag) break;
    }
    __builtin_amdgcn_sched_barrier(0);
}

// cross-block phase barrier: quad-arrive -> leader publishes cluster flag -> leader polls
// all 8 flags -> go
DEVINL void phase_bar(volatile int* hq, int* flags, int cb, int wq, int l, int tag) {
    asm volatile("s_waitcnt vmcnt(0)" ::: "memory");
    asm volatile("s_waitcnt lgkmcnt(0)" ::: "memory");
    if (l == 0) hq[wq] = tag;
    if (wq == 0 && l == 0) {
        for (;;) {
            int a0 = hq[0], a1 = hq[1], a2 = hq[2], a3 = hq[3];
            if (min(min(a0, a1), min(a2, a3)) >= tag) break;
        }
        asm volatile("global_store_dword %0, %1, off sc1" :: "v"(flags + cb), "v"(tag) : "memory");
        for (;;) {
            int4 a, b;
            asm volatile("global_load_dwordx4 %0, %2, off sc1\n\t"
                         "global_load_dwordx4 %1, %2, off offset:16 sc1\n\t"
                         "s_waitcnt vmcnt(0)"
                         : "=&v"(a), "=&v"(b) : "v"(flags) : "memory");
            int m0 = min(min(a.x, a.y), min(a.z, a.w));
            int m1 = min(min(b.x, b.y), min(b.z, b.w));
            if (min(m0, m1) >= tag) break;
        }
        hq[4] = tag;
    }
    while (hq[4] < tag) {}
    __builtin_amdgcn_sched_barrier(0);
}

__global__ __launch_bounds__(1024)
void cfc_main(const float* __restrict__ x, const float* __restrict__ ts,
              const float* __restrict__ b1g, const float* __restrict__ b2g,
              const float* __restrict__ bff1g, const float* __restrict__ bff2g,
              const float* __restrict__ btag, const float* __restrict__ btbg,
              const float* __restrict__ boutg,
              const _Float16* __restrict__ wsf,
              char* __restrict__ actbase, int* __restrict__ cntbase,
              float* __restrict__ out)
{
    extern __shared__ __align__(16) char dyn[];
    __shared__ __align__(8) _Float16 xp[16][16][20];   // per-wave transpose tiles
    __shared__ int hs[4][12];

    const int tid = threadIdx.x;
    const int l = tid & 63, w = tid >> 6;             // 16 waves
    const int q = w >> 2, wq = w & 3;                 // quad / wave-in-quad
    const int lq = wq * 64 + l;                       // thread-in-quad [0,256)
    const int lc = l & 15, lg = l >> 4;
    const int xr = l >> 2, xs = l & 3;
    const int qg = blockIdx.x >> 3, cb = blockIdx.x & 7;
    const int cluster = qg * 4 + q;
    const int r0 = cluster * 16;

    char* stgz = dyn + q * STGZ_Q;
    char* stgh = dyn + 4 * STGZ_Q + q * STGH_Q;
    float* taL = (float*)(dyn + 4 * (STGZ_Q + STGH_Q) + q * TAL_Q);  // [2][2][2][16][17]
    volatile int* hq = (volatile int*)&hs[q][0];

    const _Float16* wb = wsf + ((size_t)(cb * 4 + wq) * NSLOT) * 512 + l * 8;

    // ---- per-lane biases ----
    const int colU = cb * 64 + wq * 16 + lc;
    const int hcol = cb * 32 + (wq >> 1) * 16 + lc;
    const int colO = cb * 16 + lc;
    const float b1c = b1g[colU], b2c = b2g[colU];
    const float bf1c = bff1g[hcol], bf2c = bff2g[hcol];
    const float btac = btag[hcol], btbc = btbg[hcol];
    const float boc = boutg[colO];

    char* act = actbase + (size_t)cluster * ACT_STRIDE;
    _Float16* z1g = (_Float16*)act;               // [16][512]
    _Float16* z2g = (_Float16*)(act + 16384);     // [16][512]
    _Float16* hg  = (_Float16*)(act + 32768);     // [16][256]
    int* flags = cntbase + cluster * 8;

    // ---- prologue: hs zero, stgh zero (h(-1)=0), x(0) prefetch ----
    if (tid < 48) ((int*)hs)[tid] = 0;
    {
        int4 z = {0, 0, 0, 0};
        int row = lq >> 4, c = lq & 15;
        *(int4*)(stgh + row * 528 + c * 16) = z;
        *(int4*)(stgh + row * 528 + 256 + c * 16) = z;
    }
    f16x8 xf[4];
    {
        const float* xr_ = x + ((size_t)(r0 + lc) * Tt + 0) * Ff + lg * 8;
#pragma unroll
        for (int kt = 0; kt < 4; ++kt) {
            f32x4 xa = *(const f32x4*)(xr_ + kt * 32);
            f32x4 xb = *(const f32x4*)(xr_ + kt * 32 + 4);
            f16x8 af;
#pragma unroll
            for (int qq = 0; qq < 4; ++qq) { af[qq] = (_Float16)xa[qq]; af[4 + qq] = (_Float16)xb[qq]; }
            xf[kt] = af;
        }
    }
    __syncthreads();   // once: hs/stgh init visible to the whole block

    for (int t = 0; t < Tt; ++t) {
        // ---------- P1: z1 = lecun([x|h] @ W1 + b1)  (w1f streamed, h from stgh) ----------
        {
            f32x4 a0 = {0.f,0.f,0.f,0.f}, a1 = {0.f,0.f,0.f,0.f};
#pragma unroll
            for (int c1 = 0; c1 < 2; ++c1) {
                f16x8 wf6[6];
#pragma unroll
                for (int s = 0; s < 6; ++s) wf6[s] = *(const f16x8*)(wb + (c1 * 6 + s) * 512);
#pragma unroll
                for (int s = 0; s < 6; ++s) {
                    int kt = c1 * 6 + s;
                    f16x8 av;
                    if (kt < 4) av = xf[kt];
                    else        av = *(const f16x8*)(stgh + lc * 528 + (kt - 4) * 64 + lg * 16);
                    if (kt & 1) a1 = MFMA16(av, wf6[s], a1);
                    else        a0 = MFMA16(av, wf6[s], a0);
                }
            }
#pragma unroll
            for (int i = 0; i < 4; ++i)
                xp[w][lg * 4 + i][lc] = (_Float16)lecun_act(a0[i] + a1[i] + b1c);
            asm volatile("s_waitcnt lgkmcnt(0)" ::: "memory");
            __builtin_amdgcn_sched_barrier(0);
            f16x4 v = *(const f16x4*)&xp[w][xr][xs * 4];
            stg8_dev(z1g + xr * Uu + cb * 64 + wq * 16 + xs * 4, v);
        }
        phase_bar(hq, flags, cb, wq, l, 3 * t + 1);

        // ---------- P2: z2 = lecun(z1 @ W2 + b2)  (quad gather + streamed w2f) ----------
        {
            {
                const char* gz = (const char*)z1g + lq * 16;
                int4 g0, g1, g2, g3;
                GATHER4(g0, g1, g2, g3, gz);
                const int rw = lq >> 6, cwb = (lq & 63) * 16;
                *(int4*)(stgz + (rw + 0) * 1040 + cwb) = g0;
                *(int4*)(stgz + (rw + 4) * 1040 + cwb) = g1;
                *(int4*)(stgz + (rw + 8) * 1040 + cwb) = g2;
                *(int4*)(stgz + (rw + 12) * 1040 + cwb) = g3;
            }
            lb_bar(hq, wq, l, 3 * t + 1);
            f32x4 a0 = {0.f,0.f,0.f,0.f}, a1 = {0.f,0.f,0.f,0.f};
#pragma unroll
            for (int c2 = 0; c2 < 2; ++c2) {
                f16x8 wf8[8];
#pragma unroll
                for (int s = 0; s < 8; ++s) wf8[s] = *(const f16x8*)(wb + (12 + c2 * 8 + s) * 512);
#pragma unroll
                for (int s = 0; s < 8; ++s) {
                    int kt = c2 * 8 + s;
                    f16x8 zf = *(const f16x8*)(stgz + lc * 1040 + kt * 64 + lg * 16);
                    if (s & 1) a1 = MFMA16(zf, wf8[s], a1);
                    else       a0 = MFMA16(zf, wf8[s], a0);
                }
            }
#pragma unroll
            for (int i = 0; i < 4; ++i)
                xp[w][lg * 4 + i][lc] = (_Float16)lecun_act(a0[i] + a1[i] + b2c);
            asm volatile("s_waitcnt lgkmcnt(0)" ::: "memory");
            __builtin_amdgcn_sched_barrier(0);
            f16x4 v = *(const f16x4*)&xp[w][xr][xs * 4];
            stg8_dev(z2g + xr * Uu + cb * 64 + wq * 16 + xs * 4, v);
        }
        phase_bar(hq, flags, cb, wq, l, 3 * t + 2);

        // ---------- P3: heads + gate -> h(t)  (quad gather + streamed whf) ----------
        {
            {
                const char* gz = (const char*)z2g + lq * 16;
                int4 g0, g1, g2, g3;
                GATHER4(g0, g1, g2, g3, gz);
                const int rw = lq >> 6, cwb = (lq & 63) * 16;
                *(int4*)(stgz + (rw + 0) * 1040 + cwb) = g0;
                *(int4*)(stgz + (rw + 4) * 1040 + cwb) = g1;
                *(int4*)(stgz + (rw + 8) * 1040 + cwb) = g2;
                *(int4*)(stgz + (rw + 12) * 1040 + cwb) = g3;
            }
            lb_bar(hq, wq, l, 3 * t + 2);
            f32x4 h0 = {0.f,0.f,0.f,0.f}, h1 = {0.f,0.f,0.f,0.f};
#pragma unroll
            for (int c3 = 0; c3 < 4; ++c3) {
                f16x8 wA[4], wB[4];
#pragma unroll
                for (int s = 0; s < 4; ++s) {
                    wA[s] = *(const f16x8*)(wb + (28 + c3 * 4 + s) * 512);
                    wB[s] = *(const f16x8*)(wb + (44 + c3 * 4 + s) * 512);
                }
#pragma unroll
                for (int s = 0; s < 4; ++s) {
                    int kt = c3 * 4 + s;
                    f16x8 zf = *(const f16x8*)(stgz + lc * 1040 + kt * 64 + lg * 16);
                    h0 = MFMA16(zf, wA[s], h0);
                    h1 = MFMA16(zf, wB[s], h1);
                }
            }
            float* tb_ = taL + ((t & 1) * 2 + (wq >> 1)) * 2 * 16 * 17;
            if (wq & 1) {   // ta/tb -> LDS + pair signal
#pragma unroll
                for (int i = 0; i < 4; ++i) {
                    tb_[0 * 16 * 17 + (lg * 4 + i) * 17 + lc] = h0[i] + btac;
                    tb_[1 * 16 * 17 + (lg * 4 + i) * 17 + lc] = h1[i] + btbc;
                }
                asm volatile("s_waitcnt lgkmcnt(0)" ::: "memory");
                if (l == 0) hq[5 + (wq >> 1)] = t + 1;
            } else {        // spin partner, gate, store h
                while (hq[5 + (wq >> 1)] < t + 1) {}
                __builtin_amdgcn_sched_barrier(0);
#pragma unroll
                for (int i = 0; i < 4; ++i) {
                    int row = lg * 4 + i;
                    float tsv = ts[(size_t)(r0 + row) * Tt + t];
                    float ff1 = fast_tanh(h0[i] + bf1c);
                    float ff2 = fast_tanh(h1[i] + bf2c);
                    float ta = tb_[0 * 16 * 17 + row * 17 + lc];
                    float tb = tb_[1 * 16 * 17 + row * 17 + lc];
                    float s = fast_sigmoid(ta * (tsv * (1.0f / 256.0f)) + tb);
                    xp[w][row][lc] = (_Float16)(ff1 + s * (ff2 - ff1));
                }
                asm volatile("s_waitcnt lgkmcnt(0)" ::: "memory");
                __builtin_amdgcn_sched_barrier(0);
                f16x4 v = *(const f16x4*)&xp[w][xr][xs * 4];
                stg8_dev(hg + xr * Hh + cb * 32 + (wq >> 1) * 16 + xs * 4, v);
            }
        }
        phase_bar(hq, flags, cb, wq, l, 3 * t + 3);

        // ---------- P4: quad gather h -> stgh; x(t+1) prefetch; out(t) ----------
        {
            f32x4 xa[4], xb[4];
            if (t + 1 < Tt) {
                const float* xr_ = x + ((size_t)(r0 + lc) * Tt + (t + 1)) * Ff + lg * 8;
#pragma unroll
                for (int kt = 0; kt < 4; ++kt) {
                    xa[kt] = *(const f32x4*)(xr_ + kt * 32);
                    xb[kt] = *(const f32x4*)(xr_ + kt * 32 + 4);
                }
            }
            {
                const char* gh = (const char*)hg + lq * 16;
                int4 g0, g1;
                GATHER2(g0, g1, gh);
                const int rw = lq >> 5, cwb = (lq & 31) * 16;
                *(int4*)(stgh + (rw + 0) * 528 + cwb) = g0;
                *(int4*)(stgh + (rw + 8) * 528 + cwb) = g1;
            }
            lb_bar(hq, wq, l, 3 * t + 3);
            if (t + 1 < Tt) {
#pragma unroll
                for (int kt = 0; kt < 4; ++kt) {
                    f16x8 af;
#pragma unroll
                    for (int qq = 0; qq < 4; ++qq) { af[qq] = (_Float16)xa[kt][qq]; af[4 + qq] = (_Float16)xb[kt][qq]; }
                    xf[kt] = af;
                }
            }
            if (wq == 0) {   // out-proj: streamed wof + h from stgh
                f16x8 wo[8];
#pragma unroll
                for (int s = 0; s < 8; ++s) wo[s] = *(const f16x8*)(wb + (60 + s) * 512);
                f32x4 a0 = {0.f,0.f,0.f,0.f}, a1 = {0.f,0.f,0.f,0.f};
#pragma unroll
                for (int kt = 0; kt < 8; ++kt) {
                    f16x8 hf = *(const f16x8*)(stgh + lc * 528 + kt * 64 + lg * 16);
                    if (kt & 1) a1 = MFMA16(hf, wo[kt], a1);
                    else        a0 = MFMA16(hf, wo[kt], a0);
                }
#pragma unroll
                for (int i = 0; i < 4; ++i)
                    out[((size_t)(r0 + lg * 4 + i) * Tt + t) * OUTo + colO] = a0[i] + a1[i] + boc;
            }
        }
    }
}

extern "C" void kernel_launch(void* const* d_in, const int* in_sizes, int n_in,
                              void* d_out, int out_size, void* d_ws, size_t ws_size,
                              hipStream_t stream) {
    const float* x    = (const float*)d_in[0];
    const float* ts   = (const float*)d_in[1];
    const float* W1   = (const float*)d_in[2];
    const float* b1   = (const float*)d_in[3];
    const float* W2   = (const float*)d_in[4];
    const float* b2   = (const float*)d_in[5];
    const float* Wff1 = (const float*)d_in[6];
    const float* bff1 = (const float*)d_in[7];
    const float* Wff2 = (const float*)d_in[8];
    const float* bff2 = (const float*)d_in[9];
    const float* Wta  = (const float*)d_in[10];
    const float* bta  = (const float*)d_in[11];
    const float* Wtb  = (const float*)d_in[12];
    const float* btb  = (const float*)d_in[13];
    const float* Wout = (const float*)d_in[14];
    const float* bout = (const float*)d_in[15];
    float* out = (float*)d_out;

    _Float16* wf = (_Float16*)d_ws;
    char* act = (char*)d_ws + ACT_OFF;
    int* cnt = (int*)((char*)d_ws + CNT_OFF);

    hipFuncSetAttribute((const void*)cfc_main,
                        hipFuncAttributeMaxDynamicSharedMemorySize, DYN_BYTES);
    hipMemsetAsync(cnt, 0, CNT_BYTES, stream);
    prep_weights<<<(NFRAG * 512) / 256, 256, 0, stream>>>(W1, W2, Wff1, Wff2, Wta, Wtb, Wout, wf);
    cfc_main<<<64, 1024, DYN_BYTES, stream>>>(x, ts, b1, b2, bff1, bff2, bta, btb, bout,
                                              wf, act, cnt, out);
}

// Round 18
// 9563.824 us; speedup vs baseline: 1.2377x; 1.2377x over previous
//
#include <hip/hip_runtime.h>

typedef _Float16 f16x8 __attribute__((ext_vector_type(8)));
typedef _Float16 f16x4 __attribute__((ext_vector_type(4)));
typedef float    f32x4 __attribute__((ext_vector_type(4)));

#define DEVINL __device__ __forceinline__

namespace {
constexpr int Tt = 256, Ff = 128, Hh = 256, Uu = 512, OUTo = 128;
constexpr int NCLUST = 32;               // 512 / 16 row-groups
constexpr int CBLK = 4;                  // blocks per cluster (512 threads each)
constexpr int NSLOT = 68;                // frags per (cb,w): 12 W1 + 16 W2 + 32 heads + 8 Wout
constexpr int NFRAG = CBLK * 8 * NSLOT;  // 2176
constexpr size_t WFRAG_BYTES = (size_t)NFRAG * 1024;
constexpr size_t ACT_OFF = WFRAG_BYTES;
constexpr size_t ACT_STRIDE = 40960;     // z1 16K | z2 16K | h 8K (+pad)
constexpr size_t CNT_OFF = ACT_OFF + (size_t)NCLUST * ACT_STRIDE;
constexpr size_t CNT_BYTES = (size_t)NCLUST * 8 * 4;   // 4 flag slots used per cluster
}

// ---- weight prep: f32 row-major -> per-(cb,w) fp16 MFMA fragment banks ----
__global__ void prep_weights(const float* __restrict__ W1, const float* __restrict__ W2,
                             const float* __restrict__ Wff1, const float* __restrict__ Wff2,
                             const float* __restrict__ Wta, const float* __restrict__ Wtb,
                             const float* __restrict__ Wout, _Float16* __restrict__ ws)
{
    int o = blockIdx.x * blockDim.x + threadIdx.x;
    if (o >= NFRAG * 512) return;
    int j = o & 7, l = (o >> 3) & 63, r = o >> 9;
    int slot = r % NSLOT, bw = r / NSLOT;
    int w = bw & 7, cb = bw >> 3;        // 8 waves, 4 blocks
    int k_in = ((l >> 4) << 3) + j, lc = l & 15;
    float v;
    if (slot < 12) {
        int kt = slot;
        v = W1[(kt * 32 + k_in) * Uu + cb * 128 + w * 16 + lc];
    } else if (slot < 28) {
        int kt = slot - 12;
        v = W2[(kt * 32 + k_in) * Uu + cb * 128 + w * 16 + lc];
    } else if (slot < 60) {
        int s = slot - 28, hpL = s >> 4, kt = s & 15;
        int head = (w & 1) * 2 + hpL;
        const float* W = (head == 0) ? Wff1 : (head == 1) ? Wff2 : (head == 2) ? Wta : Wtb;
        v = W[(kt * 32 + k_in) * Hh + cb * 64 + (w >> 1) * 16 + lc];
    } else {
        int kt = slot - 60;
        v = (w < 2) ? Wout[(kt * 32 + k_in) * OUTo + cb * 32 + w * 16 + lc] : 0.0f;
    }
    ws[o] = (_Float16)v;
}

DEVINL float fast_tanh(float v) {
    float e = __expf(2.0f * v);
    return 1.0f - 2.0f / (e + 1.0f);
}
DEVINL float fast_sigmoid(float v) { return 1.0f / (1.0f + __expf(-v)); }
DEVINL float lecun_act(float v)    { return 1.7159f * fast_tanh(0.666f * v); }

// ---- device-scope (sc1) accessors ----
DEVINL void stg8_dev(_Float16* p, f16x4 v) {
    asm volatile("global_store_dwordx2 %0, %1, off sc1" :: "v"(p), "v"(v) : "memory");
}

#define GATHER2F(g0, g1, base) \
    asm volatile( \
        "global_load_dwordx4 %0, %2, off sc1\n\t" \
        "global_load_dwordx4 %1, %3, off sc1\n\t" \
        "s_waitcnt vmcnt(0)" \
        : "=&v"(g0), "=&v"(g1) \
        : "v"(base), "v"((base) + 8192) \
        : "memory")

#define GATHER1F(g0, base) \
    asm volatile( \
        "global_load_dwordx4 %0, %1, off sc1\n\t" \
        "s_waitcnt vmcnt(0)" \
        : "=&v"(g0) : "v"(base) : "memory")

#define MFMA16(a, b, c) __builtin_amdgcn_mfma_f32_16x16x32_f16(a, b, c, 0, 0, 0)

// arrive: drain all stores, block-sync, thread0 publishes monotone tag (device scope)
DEVINL void arrive(int* flags, int cb, int tag, int tid) {
    asm volatile("s_waitcnt vmcnt(0)" ::: "memory");
    __syncthreads();
    if (tid == 0)
        asm volatile("global_store_dword %0, %1, off sc1" :: "v"(flags + cb), "v"(tag) : "memory");
}
// wait: thread0 polls the 4 flags (one dwordx4)
DEVINL void waitf(int* flags, int tag, int tid) {
    if (tid == 0) {
        for (;;) {
            int4 a;
            asm volatile("global_load_dwordx4 %0, %1, off sc1\n\t"
                         "s_waitcnt vmcnt(0)"
                         : "=&v"(a) : "v"(flags) : "memory");
            if (min(min(a.x, a.y), min(a.z, a.w)) >= tag) break;
        }
    }
    __syncthreads();
    __builtin_amdgcn_sched_barrier(0);
}

__global__ __launch_bounds__(512, 1)
void cfc_main(const float* __restrict__ x, const float* __restrict__ ts,
              const float* __restrict__ b1g, const float* __restrict__ b2g,
              const float* __restrict__ bff1g, const float* __restrict__ bff2g,
              const float* __restrict__ btag, const float* __restrict__ btbg,
              const float* __restrict__ boutg,
              const _Float16* __restrict__ wsf,
              char* __restrict__ actbase, int* __restrict__ cntbase,
              float* __restrict__ out)
{
    __shared__ float taL[2][4][2][16][17];            // [t&1][coltile][ta/tb][row][col]
    __shared__ __align__(8) _Float16 xp[8][16][20];   // per-wave transpose tiles
    __shared__ __align__(16) char stg[16 * 1040];     // staged activation tile (padded)

    const int tid = threadIdx.x;
    const int l = tid & 63, w = tid >> 6;             // 8 waves
    const int lc = l & 15, lg = l >> 4;
    const int xr = l >> 2, xs = l & 3;                // xpose readback row/seg
    const int cluster = blockIdx.x & 31;
    const int cb = blockIdx.x >> 5;                   // 0..3
    const int r0 = cluster * 16;

    // ---- weight fragments -> registers ----
    // w1f/w2f (112 regs) arch VGPRs; whf/wof (160 regs) AGPRs (proven R14 split).
    const _Float16* wb = wsf + ((size_t)(cb * 8 + w) * NSLOT) * 512 + l * 8;
    f16x8 w1f[12], w2f[16], whf[32], wof[8];
#pragma unroll
    for (int s = 0; s < 12; ++s) w1f[s] = *(const f16x8*)(wb + s * 512);
#pragma unroll
    for (int s = 0; s < 16; ++s) w2f[s] = *(const f16x8*)(wb + (12 + s) * 512);
#pragma unroll
    for (int s = 0; s < 32; ++s) whf[s] = *(const f16x8*)(wb + (28 + s) * 512);
#pragma unroll
    for (int s = 0; s < 8; ++s)  wof[s] = *(const f16x8*)(wb + (60 + s) * 512);

    // ---- per-lane biases ----
    const int colU = cb * 128 + w * 16 + lc;
    const int hcol = cb * 64 + (w >> 1) * 16 + lc;
    const int colO = cb * 32 + (w & 1) * 16 + lc;     // valid for w<2
    const float b1c = b1g[colU], b2c = b2g[colU];
    const float bf1c = bff1g[hcol], bf2c = bff2g[hcol];
    const float btac = btag[hcol], btbc = btbg[hcol];
    const float boc = boutg[(w < 2) ? colO : 0];

    char* act = actbase + (size_t)cluster * ACT_STRIDE;
    _Float16* z1g = (_Float16*)act;               // [16][512]
    _Float16* z2g = (_Float16*)(act + 16384);     // [16][512]
    _Float16* hg  = (_Float16*)(act + 32768);     // [16][256]
    int* flags = cntbase + cluster * 8;           // slots 0..3

    f16x8 hfrag[8];
#pragma unroll
    for (int s = 0; s < 8; ++s) hfrag[s] = f16x8{0,0,0,0,0,0,0,0};

    f16x8 xf[4];
    {
        const float* xr_ = x + ((size_t)(r0 + lc) * Tt + 0) * Ff + lg * 8;
#pragma unroll
        for (int kt = 0; kt < 4; ++kt) {
            f32x4 xa = *(const f32x4*)(xr_ + kt * 32);
            f32x4 xb = *(const f32x4*)(xr_ + kt * 32 + 4);
            f16x8 af;
#pragma unroll
            for (int q = 0; q < 4; ++q) { af[q] = (_Float16)xa[q]; af[4 + q] = (_Float16)xb[q]; }
            xf[kt] = af;
        }
    }

    for (int t = 0; t < Tt; ++t) {
        // ---- pin weights resident ----
#pragma unroll
        for (int s = 0; s < 12; ++s) asm volatile("" : "+v"(w1f[s]));
#pragma unroll
        for (int s = 0; s < 16; ++s) asm volatile("" : "+v"(w2f[s]));
#pragma unroll
        for (int s = 0; s < 32; ++s) asm volatile("" : "+a"(whf[s]));
#pragma unroll
        for (int s = 0; s < 8; ++s)  asm volatile("" : "+a"(wof[s]));

        // ---------- P1: z1 = lecun([x|h] @ W1 + b1) ----------
        {
            f32x4 a0 = {0.f,0.f,0.f,0.f}, a1 = {0.f,0.f,0.f,0.f};
            a0 = MFMA16(xf[0], w1f[0], a0);  a1 = MFMA16(xf[1], w1f[1], a1);
            a0 = MFMA16(xf[2], w1f[2], a0);  a1 = MFMA16(xf[3], w1f[3], a1);
            a0 = MFMA16(hfrag[0], w1f[4], a0);  a1 = MFMA16(hfrag[1], w1f[5], a1);
            a0 = MFMA16(hfrag[2], w1f[6], a0);  a1 = MFMA16(hfrag[3], w1f[7], a1);
            a0 = MFMA16(hfrag[4], w1f[8], a0);  a1 = MFMA16(hfrag[5], w1f[9], a1);
            a0 = MFMA16(hfrag[6], w1f[10], a0); a1 = MFMA16(hfrag[7], w1f[11], a1);
#pragma unroll
            for (int i = 0; i < 4; ++i)
                xp[w][lg * 4 + i][lc] = (_Float16)lecun_act(a0[i] + a1[i] + b1c);
            asm volatile("s_waitcnt lgkmcnt(0)" ::: "memory");
            __builtin_amdgcn_sched_barrier(0);
            f16x4 v = *(const f16x4*)&xp[w][xr][xs * 4];
            stg8_dev(z1g + xr * Uu + cb * 128 + w * 16 + xs * 4, v);
        }
        arrive(flags, cb, 3 * t + 1, tid);

        // ---------- P2: z2 = lecun(z1 @ W2 + b2), staged gather ----------
        waitf(flags, 3 * t + 1, tid);
        {
            {   // cooperative 16KB gather: 512 threads x 2 x 16B
                const char* gz = (const char*)z1g + tid * 16;
                int4 g0, g1;
                GATHER2F(g0, g1, gz);
                const int rw = tid >> 6, cwb = (tid & 63) * 16;
                *(int4*)(stg + (rw + 0) * 1040 + cwb) = g0;
                *(int4*)(stg + (rw + 8) * 1040 + cwb) = g1;
            }
            __syncthreads();
            f32x4 a0 = {0.f,0.f,0.f,0.f}, a1 = {0.f,0.f,0.f,0.f};
#pragma unroll
            for (int kt = 0; kt < 16; ++kt) {
                f16x8 zf = *(const f16x8*)(stg + lc * 1040 + kt * 64 + lg * 16);
                if (kt & 1) a1 = MFMA16(zf, w2f[kt], a1);
                else        a0 = MFMA16(zf, w2f[kt], a0);
            }
#pragma unroll
            for (int i = 0; i < 4; ++i)
                xp[w][lg * 4 + i][lc] = (_Float16)lecun_act(a0[i] + a1[i] + b2c);
            asm volatile("s_waitcnt lgkmcnt(0)" ::: "memory");
            __builtin_amdgcn_sched_barrier(0);
            f16x4 v = *(const f16x4*)&xp[w][xr][xs * 4];
            stg8_dev(z2g + xr * Uu + cb * 128 + w * 16 + xs * 4, v);
        }
        arrive(flags, cb, 3 * t + 2, tid);

        // ---------- P3: heads + gate -> h(t), staged gather ----------
        waitf(flags, 3 * t + 2, tid);
        {
            {
                const char* gz = (const char*)z2g + tid * 16;
                int4 g0, g1;
                GATHER2F(g0, g1, gz);
                const int rw = tid >> 6, cwb = (tid & 63) * 16;
                *(int4*)(stg + (rw + 0) * 1040 + cwb) = g0;
                *(int4*)(stg + (rw + 8) * 1040 + cwb) = g1;
            }
            __syncthreads();
            f32x4 h0 = {0.f,0.f,0.f,0.f}, h1 = {0.f,0.f,0.f,0.f};
#pragma unroll
            for (int kt = 0; kt < 16; ++kt) {
                f16x8 zf = *(const f16x8*)(stg + lc * 1040 + kt * 64 + lg * 16);
                h0 = MFMA16(zf, whf[kt], h0);
                h1 = MFMA16(zf, whf[16 + kt], h1);
            }
            if (w & 1) {          // ta, tb -> LDS (parity double-buffered)
#pragma unroll
                for (int i = 0; i < 4; ++i) {
                    taL[t & 1][w >> 1][0][lg * 4 + i][lc] = h0[i] + btac;
                    taL[t & 1][w >> 1][1][lg * 4 + i][lc] = h1[i] + btbc;
                }
            }
            __syncthreads();
            if (!(w & 1)) {       // ff1, ff2 + gate + h store
#pragma unroll
                for (int i = 0; i < 4; ++i) {
                    int row = lg * 4 + i;
                    float tsv = ts[(size_t)(r0 + row) * Tt + t];
                    float ff1 = fast_tanh(h0[i] + bf1c);
                    float ff2 = fast_tanh(h1[i] + bf2c);
                    float ta = taL[t & 1][w >> 1][0][row][lc];
                    float tb = taL[t & 1][w >> 1][1][row][lc];
                    float s = fast_sigmoid(ta * (tsv * (1.0f / 256.0f)) + tb);
                    xp[w][row][lc] = (_Float16)(ff1 + s * (ff2 - ff1));
                }
                asm volatile("s_waitcnt lgkmcnt(0)" ::: "memory");
                __builtin_amdgcn_sched_barrier(0);
                f16x4 v = *(const f16x4*)&xp[w][xr][xs * 4];
                stg8_dev(hg + xr * Hh + cb * 64 + (w >> 1) * 16 + xs * 4, v);
            }
        }
        arrive(flags, cb, 3 * t + 3, tid);

        // ---------- P4: staged h gather; x(t+1) prefetch; out(t) ----------
        waitf(flags, 3 * t + 3, tid);
        {
            f32x4 xa[4], xb[4];
            if (t + 1 < Tt) {
                const float* xr_ = x + ((size_t)(r0 + lc) * Tt + (t + 1)) * Ff + lg * 8;
#pragma unroll
                for (int kt = 0; kt < 4; ++kt) {
                    xa[kt] = *(const f32x4*)(xr_ + kt * 32);
                    xb[kt] = *(const f32x4*)(xr_ + kt * 32 + 4);
                }
            }
            {   // cooperative 8KB gather: 512 threads x 16B
                const char* gh = (const char*)hg + tid * 16;
                int4 g0;
                GATHER1F(g0, gh);
                const int rw = tid >> 5, cwb = (tid & 31) * 16;
                *(int4*)(stg + rw * 528 + cwb) = g0;
            }
            __syncthreads();
#pragma unroll
            for (int kt = 0; kt < 8; ++kt)
                hfrag[kt] = *(const f16x8*)(stg + lc * 528 + kt * 64 + lg * 16);
            if (t + 1 < Tt) {
#pragma unroll
                for (int kt = 0; kt < 4; ++kt) {
                    f16x8 af;
#pragma unroll
                    for (int q = 0; q < 4; ++q) { af[q] = (_Float16)xa[kt][q]; af[4 + q] = (_Float16)xb[kt][q]; }
                    xf[kt] = af;
                }
            }
            if (w < 2) {   // out-proj: 2 waves cover 32 cols of this block
                f32x4 a0 = {0.f,0.f,0.f,0.f}, a1 = {0.f,0.f,0.f,0.f};
                a0 = MFMA16(hfrag[0], wof[0], a0); a1 = MFMA16(hfrag[1], wof[1], a1);
                a0 = MFMA16(hfrag[2], wof[2], a0); a1 = MFMA16(hfrag[3], wof[3], a1);
                a0 = MFMA16(hfrag[4], wof[4], a0); a1 = MFMA16(hfrag[5], wof[5], a1);
                a0 = MFMA16(hfrag[6], wof[6], a0); a1 = MFMA16(hfrag[7], wof[7], a1);
#pragma unroll
                for (int i = 0; i < 4; ++i)
                    out[((size_t)(r0 + lg * 4 + i) * Tt + t) * OUTo + colO] = a0[i] + a1[i] + boc;
            }
        }
    }
}

extern "C" void kernel_launch(void* const* d_in, const int* in_sizes, int n_in,
                              void* d_out, int out_size, void* d_ws, size_t ws_size,
                              hipStream_t stream) {
    const float* x    = (const float*)d_in[0];
    const float* ts   = (const float*)d_in[1];
    const float* W1   = (const float*)d_in[2];
    const float* b1   = (const float*)d_in[3];
    const float* W2   = (const float*)d_in[4];
    const float* b2   = (const float*)d_in[5];
    const float* Wff1 = (const float*)d_in[6];
    const float* bff1 = (const float*)d_in[7];
    const float* Wff2 = (const float*)d_in[8];
    const float* bff2 = (const float*)d_in[9];
    const float* Wta  = (const float*)d_in[10];
    const float* bta  = (const float*)d_in[11];
    const float* Wtb  = (const float*)d_in[12];
    const float* btb  = (const float*)d_in[13];
    const float* Wout = (const float*)d_in[14];
    const float* bout = (const float*)d_in[15];
    float* out = (float*)d_out;

    _Float16* wf = (_Float16*)d_ws;
    char* act = (char*)d_ws + ACT_OFF;
    int* cnt = (int*)((char*)d_ws + CNT_OFF);

    hipMemsetAsync(cnt, 0, CNT_BYTES, stream);
    prep_weights<<<(NFRAG * 512) / 256, 256, 0, stream>>>(W1, W2, Wff1, Wff2, Wta, Wtb, Wout, wf);
    cfc_main<<<NCLUST * CBLK, 512, 0, stream>>>(x, ts, b1, b2, bff1, bff2, bta, btb, bout,
                                                wf, act, cnt, out);
}

// Round 19
// 3856.296 us; speedup vs baseline: 3.0696x; 2.4801x over previous
//
#include <hip/hip_runtime.h>

typedef _Float16 f16x8 __attribute__((ext_vector_type(8)));
typedef _Float16 f16x4 __attribute__((ext_vector_type(4)));
typedef float    f32x4 __attribute__((ext_vector_type(4)));

#define DEVINL __device__ __forceinline__

namespace {
constexpr int Tt = 256, Ff = 128, Hh = 256, Uu = 512, OUTo = 128;
constexpr int NCLUST = 32;               // 512 / 16 row-groups
constexpr int CBLK = 8;                  // blocks per cluster
constexpr int NPAIR = 16;                // cluster pairs per block column
constexpr int NSLOT = 68;                // frags per (cb,w): 12 W1 + 16 W2 + 32 heads + 8 Wout
constexpr int NFRAG = CBLK * 4 * NSLOT;  // 2176
constexpr size_t WFRAG_BYTES = (size_t)NFRAG * 1024;
constexpr size_t ACT_OFF = WFRAG_BYTES;
constexpr size_t ACT_STRIDE = 40960;     // z1 16K | z2 16K | h 8K (+pad)
constexpr size_t CNT_OFF = ACT_OFF + (size_t)NCLUST * ACT_STRIDE;
constexpr size_t CNT_BYTES = (size_t)NCLUST * 8 * 4;
}

// ---- weight prep: f32 row-major -> per-(cb,w) fp16 MFMA fragment banks (R15 layout) ----
__global__ void prep_weights(const float* __restrict__ W1, const float* __restrict__ W2,
                             const float* __restrict__ Wff1, const float* __restrict__ Wff2,
                             const float* __restrict__ Wta, const float* __restrict__ Wtb,
                             const float* __restrict__ Wout, _Float16* __restrict__ ws)
{
    int o = blockIdx.x * blockDim.x + threadIdx.x;
    if (o >= NFRAG * 512) return;
    int j = o & 7, l = (o >> 3) & 63, r = o >> 9;
    int slot = r % NSLOT, bw = r / NSLOT;
    int w = bw & 3, cb = bw >> 2;
    int k_in = ((l >> 4) << 3) + j, lc = l & 15;
    float v;
    if (slot < 12) {
        int kt = slot;
        v = W1[(kt * 32 + k_in) * Uu + cb * 64 + w * 16 + lc];
    } else if (slot < 28) {
        int kt = slot - 12;
        v = W2[(kt * 32 + k_in) * Uu + cb * 64 + w * 16 + lc];
    } else if (slot < 60) {
        int s = slot - 28, hpL = s >> 4, kt = s & 15;
        int head = (w & 1) * 2 + hpL;
        const float* W = (head == 0) ? Wff1 : (head == 1) ? Wff2 : (head == 2) ? Wta : Wtb;
        v = W[(kt * 32 + k_in) * Hh + cb * 32 + (w >> 1) * 16 + lc];
    } else {
        int kt = slot - 60;
        v = Wout[(kt * 32 + k_in) * OUTo + cb * 16 + lc];
    }
    ws[o] = (_Float16)v;
}

DEVINL float fast_tanh(float v) {
    float e = __expf(2.0f * v);
    return 1.0f - 2.0f / (e + 1.0f);
}
DEVINL float fast_sigmoid(float v) { return 1.0f / (1.0f + __expf(-v)); }
DEVINL float lecun_act(float v)    { return 1.7159f * fast_tanh(0.666f * v); }

// ---- device-scope (sc1) accessors ----
DEVINL void stg8_dev(_Float16* p, f16x4 v) {
    asm volatile("global_store_dwordx2 %0, %1, off sc1" :: "v"(p), "v"(v) : "memory");
}

#define GATHER4(g0, g1, g2, g3, base) \
    asm volatile( \
        "global_load_dwordx4 %0, %4, off sc1\n\t" \
        "global_load_dwordx4 %1, %5, off sc1\n\t" \
        "global_load_dwordx4 %2, %6, off sc1\n\t" \
        "global_load_dwordx4 %3, %7, off sc1\n\t" \
        "s_waitcnt vmcnt(0)" \
        : "=&v"(g0), "=&v"(g1), "=&v"(g2), "=&v"(g3) \
        : "v"(base), "v"((base) + 4096), "v"((base) + 8192), "v"((base) + 12288) \
        : "memory")

#define GATHER2(g0, g1, base) \
    asm volatile( \
        "global_load_dwordx4 %0, %2, off sc1\n\t" \
        "global_load_dwordx4 %1, %3, off sc1\n\t" \
        "s_waitcnt vmcnt(0)" \
        : "=&v"(g0), "=&v"(g1) \
        : "v"(base), "v"((base) + 4096) \
        : "memory")

#define MFMA16(a, b, c) __builtin_amdgcn_mfma_f32_16x16x32_f16(a, b, c, 0, 0, 0)

// arrive: drain all my stores, block-sync, thread0 publishes monotone tag (device scope)
DEVINL void arrive(int* flags, int cb, int tag, int tid) {
    asm volatile("s_waitcnt vmcnt(0)" ::: "memory");
    __syncthreads();
    if (tid == 0)
        asm volatile("global_store_dword %0, %1, off sc1" :: "v"(flags + cb), "v"(tag) : "memory");
}
// wait: thread0 polls all 8 flags >= tag
DEVINL void waitf(int* flags, int tag, int tid) {
    if (tid == 0) {
        for (;;) {
            int4 a, b;
            asm volatile("global_load_dwordx4 %0, %2, off sc1\n\t"
                         "global_load_dwordx4 %1, %2, off offset:16 sc1\n\t"
                         "s_waitcnt vmcnt(0)"
                         : "=&v"(a), "=&v"(b) : "v"(flags) : "memory");
            int m0 = min(min(a.x, a.y), min(a.z, a.w));
            int m1 = min(min(b.x, b.y), min(b.z, b.w));
            if (min(m0, m1) >= tag) break;
        }
    }
    __syncthreads();
    __builtin_amdgcn_sched_barrier(0);
}

// ---------------- per-group phases (S in {A,B}) ----------------
// P1: wait h(t-1) flag; staged gather h -> stghS; z1 = lecun([x|h]@W1+b1)
#define PHASE1(S, T) do { \
    waitf(flags##S, 3 * (T), tid); \
    { \
        const char* gh = (const char*)hg##S + tid * 16; \
        int4 g0, g1; \
        GATHER2(g0, g1, gh); \
        const int rw = tid >> 5, cwb = (tid & 31) * 16; \
        *(int4*)(stgh##S + (rw + 0) * 528 + cwb) = g0; \
        *(int4*)(stgh##S + (rw + 8) * 528 + cwb) = g1; \
    } \
    __syncthreads(); \
    f32x4 a0 = {0.f,0.f,0.f,0.f}, a1 = {0.f,0.f,0.f,0.f}; \
    a0 = MFMA16(xf##S[0], w1f[0], a0);  a1 = MFMA16(xf##S[1], w1f[1], a1); \
    a0 = MFMA16(xf##S[2], w1f[2], a0);  a1 = MFMA16(xf##S[3], w1f[3], a1); \
    _Pragma("unroll") \
    for (int kt = 4; kt < 12; ++kt) { \
        f16x8 hf = *(const f16x8*)(stgh##S + lc * 528 + (kt - 4) * 64 + lg * 16); \
        if (kt & 1) a1 = MFMA16(hf, w1f[kt], a1); \
        else        a0 = MFMA16(hf, w1f[kt], a0); \
    } \
    _Pragma("unroll") \
    for (int i = 0; i < 4; ++i) \
        xp[w][lg * 4 + i][lc] = (_Float16)lecun_act(a0[i] + a1[i] + b1c); \
    asm volatile("s_waitcnt lgkmcnt(0)" ::: "memory"); \
    __builtin_amdgcn_sched_barrier(0); \
    f16x4 v = *(const f16x4*)&xp[w][xr][xs * 4]; \
    stg8_dev(z1g##S + xr * Uu + cb * 64 + w * 16 + xs * 4, v); \
    arrive(flags##S, cb, 3 * (T) + 1, tid); \
} while (0)

#define PHASE2(S, T) do { \
    waitf(flags##S, 3 * (T) + 1, tid); \
    { \
        const char* gz = (const char*)z1g##S + tid * 16; \
        int4 g0, g1, g2, g3; \
        GATHER4(g0, g1, g2, g3, gz); \
        const int rw = tid >> 6, cwb = (tid & 63) * 16; \
        *(int4*)(stg + (rw + 0) * 1040 + cwb) = g0; \
        *(int4*)(stg + (rw + 4) * 1040 + cwb) = g1; \
        *(int4*)(stg + (rw + 8) * 1040 + cwb) = g2; \
        *(int4*)(stg + (rw + 12) * 1040 + cwb) = g3; \
    } \
    __syncthreads(); \
    f32x4 a0 = {0.f,0.f,0.f,0.f}, a1 = {0.f,0.f,0.f,0.f}; \
    _Pragma("unroll") \
    for (int kt = 0; kt < 16; ++kt) { \
        f16x8 zf = *(const f16x8*)(stg + lc * 1040 + kt * 64 + lg * 16); \
        if (kt & 1) a1 = MFMA16(zf, w2f[kt], a1); \
        else        a0 = MFMA16(zf, w2f[kt], a0); \
    } \
    _Pragma("unroll") \
    for (int i = 0; i < 4; ++i) \
        xp[w][lg * 4 + i][lc] = (_Float16)lecun_act(a0[i] + a1[i] + b2c); \
    asm volatile("s_waitcnt lgkmcnt(0)" ::: "memory"); \
    __builtin_amdgcn_sched_barrier(0); \
    f16x4 v = *(const f16x4*)&xp[w][xr][xs * 4]; \
    stg8_dev(z2g##S + xr * Uu + cb * 64 + w * 16 + xs * 4, v); \
    arrive(flags##S, cb, 3 * (T) + 2, tid); \
} while (0)

// P3: wait z2; gather; x(t+1) prefetch; heads+gate -> h; store h to hgS (sc1) and hsb (cached)
#define PHASE3(S, T) do { \
    waitf(flags##S, 3 * (T) + 2, tid); \
    f32x4 xa[4], xb[4]; \
    if ((T) + 1 < Tt) { \
        const float* xr_ = x + ((size_t)(r0##S + lc) * Tt + ((T) + 1)) * Ff + lg * 8; \
        _Pragma("unroll") \
        for (int kt = 0; kt < 4; ++kt) { \
            xa[kt] = *(const f32x4*)(xr_ + kt * 32); \
            xb[kt] = *(const f32x4*)(xr_ + kt * 32 + 4); \
        } \
    } \
    { \
        const char* gz = (const char*)z2g##S + tid * 16; \
        int4 g0, g1, g2, g3; \
        GATHER4(g0, g1, g2, g3, gz); \
        const int rw = tid >> 6, cwb = (tid & 63) * 16; \
        *(int4*)(stg + (rw + 0) * 1040 + cwb) = g0; \
        *(int4*)(stg + (rw + 4) * 1040 + cwb) = g1; \
        *(int4*)(stg + (rw + 8) * 1040 + cwb) = g2; \
        *(int4*)(stg + (rw + 12) * 1040 + cwb) = g3; \
    } \
    __syncthreads(); \
    f32x4 h0 = {0.f,0.f,0.f,0.f}, h1 = {0.f,0.f,0.f,0.f}; \
    _Pragma("unroll") \
    for (int kt = 0; kt < 16; ++kt) { \
        f16x8 zf = *(const f16x8*)(stg + lc * 1040 + kt * 64 + lg * 16); \
        h0 = MFMA16(zf, whf[kt], h0); \
        h1 = MFMA16(zf, whf[16 + kt], h1); \
    } \
    if (w & 1) { \
        _Pragma("unroll") \
        for (int i = 0; i < 4; ++i) { \
            taL##S[(T) & 1][w >> 1][0][lg * 4 + i][lc] = h0[i] + btac; \
            taL##S[(T) & 1][w >> 1][1][lg * 4 + i][lc] = h1[i] + btbc; \
        } \
    } \
    __syncthreads(); \
    if (!(w & 1)) { \
        _Pragma("unroll") \
        for (int i = 0; i < 4; ++i) { \
            int row = lg * 4 + i; \
            float tsv = ts[(size_t)(r0##S + row) * Tt + (T)]; \
            float ff1 = fast_tanh(h0[i] + bf1c); \
            float ff2 = fast_tanh(h1[i] + bf2c); \
            float ta = taL##S[(T) & 1][w >> 1][0][row][lc]; \
            float tb = taL##S[(T) & 1][w >> 1][1][row][lc]; \
            float s = fast_sigmoid(ta * (tsv * (1.0f / 256.0f)) + tb); \
            xp[w][row][lc] = (_Float16)(ff1 + s * (ff2 - ff1)); \
        } \
        asm volatile("s_waitcnt lgkmcnt(0)" ::: "memory"); \
        __builtin_amdgcn_sched_barrier(0); \
        f16x4 v = *(const f16x4*)&xp[w][xr][xs * 4]; \
        stg8_dev(hg##S + xr * Hh + cb * 32 + (w >> 1) * 16 + xs * 4, v); \
        *(f16x4*)(hsb + ((size_t)(r0##S + xr) * Tt + (T)) * Hh + cb * 32 + (w >> 1) * 16 + xs * 4) = v; \
    } \
    if ((T) + 1 < Tt) { \
        _Pragma("unroll") \
        for (int kt = 0; kt < 4; ++kt) { \
            f16x8 af; \
            _Pragma("unroll") \
            for (int q = 0; q < 4; ++q) { af[q] = (_Float16)xa[kt][q]; af[4 + q] = (_Float16)xb[kt][q]; } \
            xf##S[kt] = af; \
        } \
    } \
    arrive(flags##S, cb, 3 * (T) + 3, tid); \
} while (0)

__global__ __launch_bounds__(256, 1)
void cfc_main(const float* __restrict__ x, const float* __restrict__ ts,
              const float* __restrict__ b1g, const float* __restrict__ b2g,
              const float* __restrict__ bff1g, const float* __restrict__ bff2g,
              const float* __restrict__ btag, const float* __restrict__ btbg,
              const _Float16* __restrict__ wsf,
              char* __restrict__ actbase, int* __restrict__ cntbase,
              _Float16* __restrict__ hsb)
{
    __shared__ float taLA[2][2][2][16][17], taLB[2][2][2][16][17];
    __shared__ __align__(8) _Float16 xp[4][16][20];
    __shared__ __align__(16) char stg[16 * 1040];        // shared (serial use A/B)
    __shared__ __align__(16) char stghA[16 * 528], stghB[16 * 528];

    const int tid = threadIdx.x;
    const int l = tid & 63, w = tid >> 6;                // 4 waves
    const int lc = l & 15, lg = l >> 4;
    const int xr = l >> 2, xs = l & 3;
    const int pair = blockIdx.x & 15;
    const int cb = blockIdx.x >> 4;
    const int clA = pair * 2, clB = pair * 2 + 1;
    const int r0A = clA * 16, r0B = clB * 16;

    // ---- weight fragments: w1f arch VGPR (48); w2f+whf AGPR (192). No wof. ----
    const _Float16* wb = wsf + ((size_t)(cb * 4 + w) * NSLOT) * 512 + l * 8;
    f16x8 w1f[12], w2f[16], whf[32];
#pragma unroll
    for (int s = 0; s < 12; ++s) w1f[s] = *(const f16x8*)(wb + s * 512);
#pragma unroll
    for (int s = 0; s < 16; ++s) w2f[s] = *(const f16x8*)(wb + (12 + s) * 512);
#pragma unroll
    for (int s = 0; s < 32; ++s) whf[s] = *(const f16x8*)(wb + (28 + s) * 512);

    const int colU = cb * 64 + w * 16 + lc;
    const int hcol = cb * 32 + (w >> 1) * 16 + lc;
    const float b1c = b1g[colU], b2c = b2g[colU];
    const float bf1c = bff1g[hcol], bf2c = bff2g[hcol];
    const float btac = btag[hcol], btbc = btbg[hcol];

    char* actA = actbase + (size_t)clA * ACT_STRIDE;
    char* actB = actbase + (size_t)clB * ACT_STRIDE;
    _Float16* z1gA = (_Float16*)actA;
    _Float16* z2gA = (_Float16*)(actA + 16384);
    _Float16* hgA  = (_Float16*)(actA + 32768);
    _Float16* z1gB = (_Float16*)actB;
    _Float16* z2gB = (_Float16*)(actB + 16384);
    _Float16* hgB  = (_Float16*)(actB + 32768);
    int* flagsA = cntbase + clA * 8;
    int* flagsB = cntbase + clB * 8;

    f16x8 xfA[4], xfB[4];
    {
        const float* xrA = x + ((size_t)(r0A + lc) * Tt + 0) * Ff + lg * 8;
        const float* xrB = x + ((size_t)(r0B + lc) * Tt + 0) * Ff + lg * 8;
#pragma unroll
        for (int kt = 0; kt < 4; ++kt) {
            f32x4 xa = *(const f32x4*)(xrA + kt * 32);
            f32x4 xb = *(const f32x4*)(xrA + kt * 32 + 4);
            f16x8 af;
#pragma unroll
            for (int q = 0; q < 4; ++q) { af[q] = (_Float16)xa[q]; af[4 + q] = (_Float16)xb[q]; }
            xfA[kt] = af;
            xa = *(const f32x4*)(xrB + kt * 32);
            xb = *(const f32x4*)(xrB + kt * 32 + 4);
#pragma unroll
            for (int q = 0; q < 4; ++q) { af[q] = (_Float16)xa[q]; af[4 + q] = (_Float16)xb[q]; }
            xfB[kt] = af;
        }
    }

    for (int t = 0; t < Tt; ++t) {
        // ---- pin weights resident ----
#pragma unroll
        for (int s = 0; s < 12; ++s) asm volatile("" : "+v"(w1f[s]));
#pragma unroll
        for (int s = 0; s < 16; ++s) asm volatile("" : "+a"(w2f[s]));
#pragma unroll
        for (int s = 0; s < 32; ++s) asm volatile("" : "+a"(whf[s]));

        PHASE1(A, t);
        PHASE1(B, t);
        PHASE2(A, t);
        PHASE2(B, t);
        PHASE3(A, t);
        PHASE3(B, t);
    }
}

// ---- final: out = h @ Wout + bout, in place over the h-holding out buffer ----
__global__ __launch_bounds__(256)
void out_proj(const _Float16* __restrict__ wsf, const float* __restrict__ boutg,
              float* __restrict__ out)
{
    const int tid = threadIdx.x;
    const int l = tid & 63, w = tid >> 6;
    const int lc = l & 15, lg = l >> 4;
    const size_t r0 = ((size_t)blockIdx.x * 4 + w) * 16;   // 16 rows of B*T
    const _Float16* hsb = (const _Float16*)out;

    f16x8 a[8];
#pragma unroll
    for (int kt = 0; kt < 8; ++kt)
        a[kt] = *(const f16x8*)(hsb + (r0 + lc) * Hh + kt * 32 + lg * 8);

    f32x4 acc[8];
#pragma unroll
    for (int nt = 0; nt < 8; ++nt) {
        acc[nt] = f32x4{0.f, 0.f, 0.f, 0.f};
#pragma unroll
        for (int kt = 0; kt < 8; ++kt) {
            f16x8 b = *(const f16x8*)(wsf + ((size_t)(nt * 4) * NSLOT + 60 + kt) * 512 + l * 8);
            acc[nt] = MFMA16(a[kt], b, acc[nt]);
        }
    }
#pragma unroll
    for (int nt = 0; nt < 8; ++nt) {
        float bo = boutg[nt * 16 + lc];
#pragma unroll
        for (int i = 0; i < 4; ++i)
            out[(r0 + lg * 4 + i) * OUTo + nt * 16 + lc] = acc[nt][i] + bo;
    }
}

extern "C" void kernel_launch(void* const* d_in, const int* in_sizes, int n_in,
                              void* d_out, int out_size, void* d_ws, size_t ws_size,
                              hipStream_t stream) {
    const float* x    = (const float*)d_in[0];
    const float* ts   = (const float*)d_in[1];
    const float* W1   = (const float*)d_in[2];
    const float* b1   = (const float*)d_in[3];
    const float* W2   = (const float*)d_in[4];
    const float* b2   = (const float*)d_in[5];
    const float* Wff1 = (const float*)d_in[6];
    const float* bff1 = (const float*)d_in[7];
    const float* Wff2 = (const float*)d_in[8];
    const float* bff2 = (const float*)d_in[9];
    const float* Wta  = (const float*)d_in[10];
    const float* bta  = (const float*)d_in[11];
    const float* Wtb  = (const float*)d_in[12];
    const float* btb  = (const float*)d_in[13];
    const float* Wout = (const float*)d_in[14];
    const float* bout = (const float*)d_in[15];
    float* out = (float*)d_out;

    _Float16* wf = (_Float16*)d_ws;
    char* act = (char*)d_ws + ACT_OFF;
    int* cnt = (int*)((char*)d_ws + CNT_OFF);

    hipMemsetAsync(act, 0, (size_t)NCLUST * ACT_STRIDE, stream);   // h(-1) = 0
    hipMemsetAsync(cnt, 0, CNT_BYTES, stream);
    prep_weights<<<(NFRAG * 512) / 256, 256, 0, stream>>>(W1, W2, Wff1, Wff2, Wta, Wtb, Wout, wf);
    cfc_main<<<NPAIR * CBLK, 256, 0, stream>>>(x, ts, b1, b2, bff1, bff2, bta, btb,
                                               wf, act, cnt, (_Float16*)out);
    out_proj<<<(512 * Tt) / 64, 256, 0, stream>>>(wf, bout, out);
}

// Round 20
// 2053.662 us; speedup vs baseline: 5.7639x; 1.8778x over previous
//
#include <hip/hip_runtime.h>

typedef _Float16 f16x8 __attribute__((ext_vector_type(8)));
typedef _Float16 f16x4 __attribute__((ext_vector_type(4)));
typedef float    f32x4 __attribute__((ext_vector_type(4)));

#define DEVINL __device__ __forceinline__

namespace {
constexpr int Tt = 256, Ff = 128, Hh = 256, Uu = 512, OUTo = 128;
constexpr int NCLUST = 32;               // 512 / 16 row-groups
constexpr int CBLK = 8;                  // blocks per cluster
constexpr int NSLOT = 68;                // frags per (cb,w): 12 W1 + 16 W2 + 32 heads + 8 Wout
constexpr int NFRAG = CBLK * 4 * NSLOT;  // 2176
constexpr size_t WFRAG_BYTES = (size_t)NFRAG * 1024;
constexpr size_t ACT_OFF = WFRAG_BYTES;
constexpr size_t ACT_STRIDE = 40960;     // z1 16K | z2 16K | h 8K (+pad)
constexpr size_t CNT_OFF = ACT_OFF + (size_t)NCLUST * ACT_STRIDE;
constexpr size_t CNT_BYTES = (size_t)NCLUST * 8 * 4;
}

// ---- weight prep: f32 row-major -> per-(cb,w) fp16 MFMA fragment banks ----
__global__ void prep_weights(const float* __restrict__ W1, const float* __restrict__ W2,
                             const float* __restrict__ Wff1, const float* __restrict__ Wff2,
                             const float* __restrict__ Wta, const float* __restrict__ Wtb,
                             const float* __restrict__ Wout, _Float16* __restrict__ ws)
{
    int o = blockIdx.x * blockDim.x + threadIdx.x;
    if (o >= NFRAG * 512) return;
    int j = o & 7, l = (o >> 3) & 63, r = o >> 9;
    int slot = r % NSLOT, bw = r / NSLOT;
    int w = bw & 3, cb = bw >> 2;
    int k_in = ((l >> 4) << 3) + j, lc = l & 15;
    float v;
    if (slot < 12) {
        int kt = slot;
        v = W1[(kt * 32 + k_in) * Uu + cb * 64 + w * 16 + lc];
    } else if (slot < 28) {
        int kt = slot - 12;
        v = W2[(kt * 32 + k_in) * Uu + cb * 64 + w * 16 + lc];
    } else if (slot < 60) {
        int s = slot - 28, hpL = s >> 4, kt = s & 15;
        int head = (w & 1) * 2 + hpL;
        const float* W = (head == 0) ? Wff1 : (head == 1) ? Wff2 : (head == 2) ? Wta : Wtb;
        v = W[(kt * 32 + k_in) * Hh + cb * 32 + (w >> 1) * 16 + lc];
    } else {
        int kt = slot - 60;
        v = Wout[(kt * 32 + k_in) * OUTo + cb * 16 + lc];
    }
    ws[o] = (_Float16)v;
}

DEVINL float fast_tanh(float v) {
    float e = __expf(2.0f * v);
    return 1.0f - 2.0f / (e + 1.0f);
}
DEVINL float fast_sigmoid(float v) { return 1.0f / (1.0f + __expf(-v)); }
DEVINL float lecun_act(float v)    { return 1.7159f * fast_tanh(0.666f * v); }

// ---- device-scope (sc1) accessors ----
DEVINL void stg8_dev(_Float16* p, f16x4 v) {
    asm volatile("global_store_dwordx2 %0, %1, off sc1" :: "v"(p), "v"(v) : "memory");
}

#define GATHER4(g0, g1, g2, g3, base) \
    asm volatile( \
        "global_load_dwordx4 %0, %4, off sc1\n\t" \
        "global_load_dwordx4 %1, %5, off sc1\n\t" \
        "global_load_dwordx4 %2, %6, off sc1\n\t" \
        "global_load_dwordx4 %3, %7, off sc1\n\t" \
        "s_waitcnt vmcnt(0)" \
        : "=&v"(g0), "=&v"(g1), "=&v"(g2), "=&v"(g3) \
        : "v"(base), "v"((base) + 4096), "v"((base) + 8192), "v"((base) + 12288) \
        : "memory")

#define GATHER2(g0, g1, base) \
    asm volatile( \
        "global_load_dwordx4 %0, %2, off sc1\n\t" \
        "global_load_dwordx4 %1, %3, off sc1\n\t" \
        "s_waitcnt vmcnt(0)" \
        : "=&v"(g0), "=&v"(g1) \
        : "v"(base), "v"((base) + 4096) \
        : "memory")

#define MFMA16(a, b, c) __builtin_amdgcn_mfma_f32_16x16x32_f16(a, b, c, 0, 0, 0)

// arrive: drain all my stores, block-sync, thread0 publishes monotone tag (device scope)
DEVINL void arrive(int* flags, int cb, int tag, int tid) {
    asm volatile("s_waitcnt vmcnt(0)" ::: "memory");
    __syncthreads();
    if (tid == 0)
        asm volatile("global_store_dword %0, %1, off sc1" :: "v"(flags + cb), "v"(tag) : "memory");
}
// wait: thread0 polls all 8 flags >= tag
DEVINL void waitf(int* flags, int tag, int tid) {
    if (tid == 0) {
        for (;;) {
            int4 a, b;
            asm volatile("global_load_dwordx4 %0, %2, off sc1\n\t"
                         "global_load_dwordx4 %1, %2, off offset:16 sc1\n\t"
                         "s_waitcnt vmcnt(0)"
                         : "=&v"(a), "=&v"(b) : "v"(flags) : "memory");
            int m0 = min(min(a.x, a.y), min(a.z, a.w));
            int m1 = min(min(b.x, b.y), min(b.z, b.w));
            if (min(m0, m1) >= tag) break;
        }
    }
    __syncthreads();
    __builtin_amdgcn_sched_barrier(0);
}

__global__ __launch_bounds__(256, 1)
void cfc_main(const float* __restrict__ x, const float* __restrict__ ts,
              const float* __restrict__ b1g, const float* __restrict__ b2g,
              const float* __restrict__ bff1g, const float* __restrict__ bff2g,
              const float* __restrict__ btag, const float* __restrict__ btbg,
              const _Float16* __restrict__ wsf,
              char* __restrict__ actbase, int* __restrict__ cntbase,
              _Float16* __restrict__ hsb)
{
    __shared__ float taL[2][2][2][16][17];            // [t&1][hcol-tile][ta/tb][row][col]
    __shared__ __align__(8) _Float16 xp[4][16][20];   // per-wave transpose tiles
    __shared__ __align__(16) char stg[16 * 1040];     // z staging (padded)
    __shared__ __align__(16) char stgh[16 * 528];     // h staging (padded)

    const int tid = threadIdx.x;
    const int l = tid & 63, w = tid >> 6;             // 4 waves
    const int lc = l & 15, lg = l >> 4;
    const int xr = l >> 2, xs = l & 3;
    const int cluster = blockIdx.x & 31;
    const int cb = blockIdx.x >> 5;
    const int r0 = cluster * 16;

    // ---- weights: w1f arch VGPR (48); w2f+whf AGPR (192). out-proj deferred. ----
    const _Float16* wb = wsf + ((size_t)(cb * 4 + w) * NSLOT) * 512 + l * 8;
    f16x8 w1f[12], w2f[16], whf[32];
#pragma unroll
    for (int s = 0; s < 12; ++s) w1f[s] = *(const f16x8*)(wb + s * 512);
#pragma unroll
    for (int s = 0; s < 16; ++s) w2f[s] = *(const f16x8*)(wb + (12 + s) * 512);
#pragma unroll
    for (int s = 0; s < 32; ++s) whf[s] = *(const f16x8*)(wb + (28 + s) * 512);

    const int colU = cb * 64 + w * 16 + lc;
    const int hcol = cb * 32 + (w >> 1) * 16 + lc;
    const float b1c = b1g[colU], b2c = b2g[colU];
    const float bf1c = bff1g[hcol], bf2c = bff2g[hcol];
    const float btac = btag[hcol], btbc = btbg[hcol];

    char* act = actbase + (size_t)cluster * ACT_STRIDE;
    _Float16* z1g = (_Float16*)act;
    _Float16* z2g = (_Float16*)(act + 16384);
    _Float16* hg  = (_Float16*)(act + 32768);
    int* flags = cntbase + cluster * 8;

    f16x8 xf[4];
    {
        const float* xr_ = x + ((size_t)(r0 + lc) * Tt + 0) * Ff + lg * 8;
#pragma unroll
        for (int kt = 0; kt < 4; ++kt) {
            f32x4 xa = *(const f32x4*)(xr_ + kt * 32);
            f32x4 xb = *(const f32x4*)(xr_ + kt * 32 + 4);
            f16x8 af;
#pragma unroll
            for (int q = 0; q < 4; ++q) { af[q] = (_Float16)xa[q]; af[4 + q] = (_Float16)xb[q]; }
            xf[kt] = af;
        }
    }

    for (int t = 0; t < Tt; ++t) {
        // ---- pin weights resident ----
#pragma unroll
        for (int s = 0; s < 12; ++s) asm volatile("" : "+v"(w1f[s]));
#pragma unroll
        for (int s = 0; s < 16; ++s) asm volatile("" : "+a"(w2f[s]));
#pragma unroll
        for (int s = 0; s < 32; ++s) asm volatile("" : "+a"(whf[s]));

        // ---------- P1: wait h(t-1); staged h-gather; z1 = lecun([x|h]@W1+b1) ----------
        waitf(flags, 3 * t, tid);
        {
            {
                const char* gh = (const char*)hg + tid * 16;
                int4 g0, g1;
                GATHER2(g0, g1, gh);
                const int rw = tid >> 5, cwb = (tid & 31) * 16;
                *(int4*)(stgh + (rw + 0) * 528 + cwb) = g0;
                *(int4*)(stgh + (rw + 8) * 528 + cwb) = g1;
            }
            __syncthreads();
            f32x4 a0 = {0.f,0.f,0.f,0.f}, a1 = {0.f,0.f,0.f,0.f};
            a0 = MFMA16(xf[0], w1f[0], a0);  a1 = MFMA16(xf[1], w1f[1], a1);
            a0 = MFMA16(xf[2], w1f[2], a0);  a1 = MFMA16(xf[3], w1f[3], a1);
#pragma unroll
            for (int kt = 4; kt < 12; ++kt) {
                f16x8 hf = *(const f16x8*)(stgh + lc * 528 + (kt - 4) * 64 + lg * 16);
                if (kt & 1) a1 = MFMA16(hf, w1f[kt], a1);
                else        a0 = MFMA16(hf, w1f[kt], a0);
            }
#pragma unroll
            for (int i = 0; i < 4; ++i)
                xp[w][lg * 4 + i][lc] = (_Float16)lecun_act(a0[i] + a1[i] + b1c);
            asm volatile("s_waitcnt lgkmcnt(0)" ::: "memory");
            __builtin_amdgcn_sched_barrier(0);
            f16x4 v = *(const f16x4*)&xp[w][xr][xs * 4];
            stg8_dev(z1g + xr * Uu + cb * 64 + w * 16 + xs * 4, v);
        }
        arrive(flags, cb, 3 * t + 1, tid);

        // ---------- P2: wait z1; staged gather; z2 = lecun(z1@W2+b2) ----------
        waitf(flags, 3 * t + 1, tid);
        {
            {
                const char* gz = (const char*)z1g + tid * 16;
                int4 g0, g1, g2, g3;
                GATHER4(g0, g1, g2, g3, gz);
                const int rw = tid >> 6, cwb = (tid & 63) * 16;
                *(int4*)(stg + (rw + 0) * 1040 + cwb) = g0;
                *(int4*)(stg + (rw + 4) * 1040 + cwb) = g1;
                *(int4*)(stg + (rw + 8) * 1040 + cwb) = g2;
                *(int4*)(stg + (rw + 12) * 1040 + cwb) = g3;
            }
            __syncthreads();
            f32x4 a0 = {0.f,0.f,0.f,0.f}, a1 = {0.f,0.f,0.f,0.f};
#pragma unroll
            for (int kt = 0; kt < 16; ++kt) {
                f16x8 zf = *(const f16x8*)(stg + lc * 1040 + kt * 64 + lg * 16);
                if (kt & 1) a1 = MFMA16(zf, w2f[kt], a1);
                else        a0 = MFMA16(zf, w2f[kt], a0);
            }
#pragma unroll
            for (int i = 0; i < 4; ++i)
                xp[w][lg * 4 + i][lc] = (_Float16)lecun_act(a0[i] + a1[i] + b2c);
            asm volatile("s_waitcnt lgkmcnt(0)" ::: "memory");
            __builtin_amdgcn_sched_barrier(0);
            f16x4 v = *(const f16x4*)&xp[w][xr][xs * 4];
            stg8_dev(z2g + xr * Uu + cb * 64 + w * 16 + xs * 4, v);
        }
        arrive(flags, cb, 3 * t + 2, tid);

        // ---------- P3: wait z2; gather; x(t+1) prefetch; heads+gate -> h ----------
        waitf(flags, 3 * t + 2, tid);
        {
            f32x4 xa[4], xb[4];
            if (t + 1 < Tt) {
                const float* xr_ = x + ((size_t)(r0 + lc) * Tt + (t + 1)) * Ff + lg * 8;
#pragma unroll
                for (int kt = 0; kt < 4; ++kt) {
                    xa[kt] = *(const f32x4*)(xr_ + kt * 32);
                    xb[kt] = *(const f32x4*)(xr_ + kt * 32 + 4);
                }
            }
            {
                const char* gz = (const char*)z2g + tid * 16;
                int4 g0, g1, g2, g3;
                GATHER4(g0, g1, g2, g3, gz);
                const int rw = tid >> 6, cwb = (tid & 63) * 16;
                *(int4*)(stg + (rw + 0) * 1040 + cwb) = g0;
                *(int4*)(stg + (rw + 4) * 1040 + cwb) = g1;
                *(int4*)(stg + (rw + 8) * 1040 + cwb) = g2;
                *(int4*)(stg + (rw + 12) * 1040 + cwb) = g3;
            }
            __syncthreads();
            f32x4 h0 = {0.f,0.f,0.f,0.f}, h1 = {0.f,0.f,0.f,0.f};
#pragma unroll
            for (int kt = 0; kt < 16; ++kt) {
                f16x8 zf = *(const f16x8*)(stg + lc * 1040 + kt * 64 + lg * 16);
                h0 = MFMA16(zf, whf[kt], h0);
                h1 = MFMA16(zf, whf[16 + kt], h1);
            }
            if (w & 1) {
#pragma unroll
                for (int i = 0; i < 4; ++i) {
                    taL[t & 1][w >> 1][0][lg * 4 + i][lc] = h0[i] + btac;
                    taL[t & 1][w >> 1][1][lg * 4 + i][lc] = h1[i] + btbc;
                }
            }
            __syncthreads();
            if (!(w & 1)) {
#pragma unroll
                for (int i = 0; i < 4; ++i) {
                    int row = lg * 4 + i;
                    float tsv = ts[(size_t)(r0 + row) * Tt + t];
                    float ff1 = fast_tanh(h0[i] + bf1c);
                    float ff2 = fast_tanh(h1[i] + bf2c);
                    float ta = taL[t & 1][w >> 1][0][row][lc];
                    float tb = taL[t & 1][w >> 1][1][row][lc];
                    float s = fast_sigmoid(ta * (tsv * (1.0f / 256.0f)) + tb);
                    xp[w][row][lc] = (_Float16)(ff1 + s * (ff2 - ff1));
                }
                asm volatile("s_waitcnt lgkmcnt(0)" ::: "memory");
                __builtin_amdgcn_sched_barrier(0);
                f16x4 v = *(const f16x4*)&xp[w][xr][xs * 4];
                stg8_dev(hg + xr * Hh + cb * 32 + (w >> 1) * 16 + xs * 4, v);
                *(f16x4*)(hsb + ((size_t)(r0 + xr) * Tt + t) * Hh + cb * 32 + (w >> 1) * 16 + xs * 4) = v;
            }
            if (t + 1 < Tt) {
#pragma unroll
                for (int kt = 0; kt < 4; ++kt) {
                    f16x8 af;
#pragma unroll
                    for (int q = 0; q < 4; ++q) { af[q] = (_Float16)xa[kt][q]; af[4 + q] = (_Float16)xb[kt][q]; }
                    xf[kt] = af;
                }
            }
        }
        arrive(flags, cb, 3 * t + 3, tid);
    }
}

// ---- final: out = h @ Wout + bout, in place over the h-holding out buffer ----
__global__ __launch_bounds__(256)
void out_proj(const _Float16* __restrict__ wsf, const float* __restrict__ boutg,
              float* __restrict__ out)
{
    const int tid = threadIdx.x;
    const int l = tid & 63, w = tid >> 6;
    const int lc = l & 15, lg = l >> 4;
    const size_t r0 = ((size_t)blockIdx.x * 4 + w) * 16;   // 16 rows of B*T
    const _Float16* hsb = (const _Float16*)out;

    f16x8 a[8];
#pragma unroll
    for (int kt = 0; kt < 8; ++kt)
        a[kt] = *(const f16x8*)(hsb + (r0 + lc) * Hh + kt * 32 + lg * 8);

    f32x4 acc[8];
#pragma unroll
    for (int nt = 0; nt < 8; ++nt) {
        acc[nt] = f32x4{0.f, 0.f, 0.f, 0.f};
#pragma unroll
        for (int kt = 0; kt < 8; ++kt) {
            f16x8 b = *(const f16x8*)(wsf + ((size_t)(nt * 4) * NSLOT + 60 + kt) * 512 + l * 8);
            acc[nt] = MFMA16(a[kt], b, acc[nt]);
        }
    }
#pragma unroll
    for (int nt = 0; nt < 8; ++nt) {
        float bo = boutg[nt * 16 + lc];
#pragma unroll
        for (int i = 0; i < 4; ++i)
            out[(r0 + lg * 4 + i) * OUTo + nt * 16 + lc] = acc[nt][i] + bo;
    }
}

extern "C" void kernel_launch(void* const* d_in, const int* in_sizes, int n_in,
                              void* d_out, int out_size, void* d_ws, size_t ws_size,
                              hipStream_t stream) {
    const float* x    = (const float*)d_in[0];
    const float* ts   = (const float*)d_in[1];
    const float* W1   = (const float*)d_in[2];
    const float* b1   = (const float*)d_in[3];
    const float* W2   = (const float*)d_in[4];
    const float* b2   = (const float*)d_in[5];
    const float* Wff1 = (const float*)d_in[6];
    const float* bff1 = (const float*)d_in[7];
    const float* Wff2 = (const float*)d_in[8];
    const float* bff2 = (const float*)d_in[9];
    const float* Wta  = (const float*)d_in[10];
    const float* bta  = (const float*)d_in[11];
    const float* Wtb  = (const float*)d_in[12];
    const float* btb  = (const float*)d_in[13];
    const float* Wout = (const float*)d_in[14];
    const float* bout = (const float*)d_in[15];
    float* out = (float*)d_out;

    _Float16* wf = (_Float16*)d_ws;
    char* act = (char*)d_ws + ACT_OFF;
    int* cnt = (int*)((char*)d_ws + CNT_OFF);

    hipMemsetAsync(act, 0, (size_t)NCLUST * ACT_STRIDE, stream);   // h(-1) = 0
    hipMemsetAsync(cnt, 0, CNT_BYTES, stream);
    prep_weights<<<(NFRAG * 512) / 256, 256, 0, stream>>>(W1, W2, Wff1, Wff2, Wta, Wtb, Wout, wf);
    cfc_main<<<NCLUST * CBLK, 256, 0, stream>>>(x, ts, b1, b2, bff1, bff2, bta, btb,
                                                wf, act, cnt, (_Float16*)out);
    out_proj<<<(512 * Tt) / 64, 256, 0, stream>>>(wf, bout, out);
}